// Round 11
// baseline (3317.760 us; speedup 1.0000x reference)
//
#include <hip/hip_runtime.h>
#include <hip/hip_bf16.h>

#define NTOK   256
#define DMODEL 512
#define NHEAD  8
#define HD     64
#define HALF   32
#define FF     1536
#define RCFF   2048
#define VOCAB  32000
#define NLAYER 2
#define NSTEPS 4
#define EPSV   1e-6f
#define THR    0.99f

typedef __attribute__((ext_vector_type(8))) short bf16x8;
typedef __attribute__((ext_vector_type(4))) float f32x4;

// ---------------- shared-memory block for the mega kernel ----------------
struct MegaShared {
    float As[16][68];
    float Ws[16][68];
    float qs[HD];
    float ps[NTOK];
    float os[4][HD];
    float red[4];
    float red2[4];
    float hv[3];
    float hw[4];
};

// ---------------- software grid barrier (generation counter) ----------------
// All 256 blocks are resident by capacity (256 thr, ~11KB LDS -> >=4 blocks/CU
// capacity vs 1 needed), so spinning is safe. threadfence both sides gives
// cross-XCD visibility (agent-scope wb/inv).
__device__ __forceinline__ void grid_bar(unsigned* cnt, unsigned* gen) {
    __threadfence();
    __syncthreads();
    if (threadIdx.x == 0) {
        unsigned g = __hip_atomic_load(gen, __ATOMIC_ACQUIRE, __HIP_MEMORY_SCOPE_AGENT);
        unsigned a = __hip_atomic_fetch_add(cnt, 1u, __ATOMIC_ACQ_REL, __HIP_MEMORY_SCOPE_AGENT);
        if (a == 255u) {
            __hip_atomic_store(cnt, 0u, __ATOMIC_RELAXED, __HIP_MEMORY_SCOPE_AGENT);
            __hip_atomic_fetch_add(gen, 1u, __ATOMIC_RELEASE, __HIP_MEMORY_SCOPE_AGENT);
        } else {
            while (__hip_atomic_load(gen, __ATOMIC_ACQUIRE, __HIP_MEMORY_SCOPE_AGENT) == g)
                __builtin_amdgcn_s_sleep(2);
        }
    }
    __syncthreads();
    __threadfence();
}

__global__ void k_barinit(unsigned* bar) { bar[0] = 0u; bar[1] = 0u; }

// ---------------- stage bodies (verbatim from round-10 kernels) ----------------
__device__ void dev_embed_norm(MegaShared& sm, int row, const int* ids,
                               const float* emb, const float* w,
                               float* x, float* xn) {
    int t = threadIdx.x;
    int id = ids[row];
    const float* er = emb + (size_t)id * DMODEL;
    float v0 = er[t], v1 = er[t + 256];
    float ss = v0 * v0 + v1 * v1;
    int lane = t & 63, wv = t >> 6;
    for (int o = 32; o > 0; o >>= 1) ss += __shfl_xor(ss, o);
    if (lane == 0) sm.red[wv] = ss;
    __syncthreads();
    float tot = sm.red[0] + sm.red[1] + sm.red[2] + sm.red[3];
    float scale = rsqrtf(tot * (1.f / DMODEL) + EPSV);
    size_t base = (size_t)row * DMODEL;
    x[base + t] = v0;
    x[base + t + 256] = v1;
    xn[base + t] = v0 * scale * w[t];
    xn[base + t + 256] = v1 * scale * w[t + 256];
}

__device__ void dev_rmsnorm(MegaShared& sm, int row, const float* in,
                            const float* w, float* out) {
    const float* xr = in + (size_t)row * DMODEL;
    float s = 0.f;
    for (int d = threadIdx.x; d < DMODEL; d += 256) { float v = xr[d]; s += v * v; }
    int lane = threadIdx.x & 63, wv = threadIdx.x >> 6;
    for (int o = 32; o > 0; o >>= 1) s += __shfl_xor(s, o);
    if (lane == 0) sm.red[wv] = s;
    __syncthreads();
    float tot = sm.red[0] + sm.red[1] + sm.red[2] + sm.red[3];
    float scale = rsqrtf(tot * (1.f / DMODEL) + EPSV);
    for (int d = threadIdx.x; d < DMODEL; d += 256)
        out[(size_t)row * DMODEL + d] = xr[d] * scale * w[d];
    __syncthreads();
}

// 64x64 split-K partial tile (verbatim k_mm_part inner); cpz pre-offset by z.
__device__ void dev_mm_tile(MegaShared& sm, const float* A, const float* W,
                            float* cpz, int K, int N, int kc,
                            int bn, int bm, int kz) {
    const int tx = threadIdx.x & 15;
    const int ty = threadIdx.x >> 4;
    float acc[4][4] = {};
    for (int k0 = kz; k0 < kz + kc; k0 += 16) {
#pragma unroll
        for (int r = 0; r < 4; ++r) {
            int idx = threadIdx.x + r * 256;
            int m = idx >> 4, kk = idx & 15;
            sm.As[kk][m] = A[(size_t)(bm + m) * K + k0 + kk];
            int n = idx & 63, kw = idx >> 6;
            sm.Ws[kw][n] = W[(size_t)(k0 + kw) * N + bn + n];
        }
        __syncthreads();
#pragma unroll
        for (int kk = 0; kk < 16; ++kk) {
            float4 av = *(const float4*)&sm.As[kk][ty * 4];
            float4 bv = *(const float4*)&sm.Ws[kk][tx * 4];
            float a[4] = {av.x, av.y, av.z, av.w};
            float b[4] = {bv.x, bv.y, bv.z, bv.w};
#pragma unroll
            for (int i = 0; i < 4; ++i)
#pragma unroll
                for (int j = 0; j < 4; ++j)
                    acc[i][j] = fmaf(a[i], b[j], acc[i][j]);
        }
        __syncthreads();
    }
#pragma unroll
    for (int i = 0; i < 4; ++i) {
        int m = bm + ty * 4 + i;
#pragma unroll
        for (int j = 0; j < 4; ++j)
            cpz[(size_t)m * N + bn + tx * 4 + j] = acc[i][j];
    }
}

__device__ void dev_qkv_rope(int pos, const float* Cp, float* qkv) {
    int t = threadIdx.x;
    int h = t >> 5, d = t & 31;
    size_t base = (size_t)pos * FF;
    auto S = [&](int col) {
        float s = 0.f;
#pragma unroll
        for (int z = 0; z < 4; ++z) s += Cp[(size_t)z * (NTOK * FF) + base + col];
        return s;
    };
    int cq0 = h * HD + d, cq1 = cq0 + HALF;
    int ck0 = DMODEL + cq0, ck1 = ck0 + HALF;
    int cv0 = 2 * DMODEL + t, cv1 = cv0 + 256;
    float q0 = S(cq0), q1 = S(cq1);
    float k0 = S(ck0), k1 = S(ck1);
    float v0 = S(cv0), v1 = S(cv1);
    float inv = powf(10000.f, -(float)d / 32.f);
    float ang = (float)pos * inv;
    float c = cosf(ang), s = sinf(ang);
    qkv[base + cq0] = q0 * c - q1 * s;
    qkv[base + cq1] = q0 * s + q1 * c;
    qkv[base + ck0] = k0 * c - k1 * s;
    qkv[base + ck1] = k0 * s + k1 * c;
    qkv[base + cv0] = v0;
    qkv[base + cv1] = v1;
}

__device__ void dev_attn(MegaShared& sm, int h, int qi,
                         const float* qkv, float* out) {
    int t = threadIdx.x;
    if (t < HD) sm.qs[t] = qkv[(size_t)qi * FF + h * HD + t];
    __syncthreads();
    float sc = -1e30f;
    if (t <= qi) {
        const float* kr = qkv + (size_t)t * FF + DMODEL + h * HD;
        float s = 0.f;
        for (int d = 0; d < HD; ++d) s = fmaf(sm.qs[d], kr[d], s);
        sc = s * 0.125f;
    }
    float m = sc;
    for (int o = 32; o > 0; o >>= 1) m = fmaxf(m, __shfl_xor(m, o));
    int lane = t & 63, wv = t >> 6;
    if (lane == 0) sm.red[wv] = m;
    __syncthreads();
    m = fmaxf(fmaxf(sm.red[0], sm.red[1]), fmaxf(sm.red[2], sm.red[3]));
    float e = (t <= qi) ? expf(sc - m) : 0.f;
    sm.ps[t] = e;
    float sum = e;
    for (int o = 32; o > 0; o >>= 1) sum += __shfl_xor(sum, o);
    if (lane == 0) sm.red2[wv] = sum;
    __syncthreads();
    sum = sm.red2[0] + sm.red2[1] + sm.red2[2] + sm.red2[3];
    float inv = 1.f / sum;
    int d = t & 63, g = t >> 6;
    float acc = 0.f;
    for (int ki = g; ki <= qi; ki += 4)
        acc = fmaf(sm.ps[ki], qkv[(size_t)ki * FF + 2 * DMODEL + h * HD + d], acc);
    sm.os[g][d] = acc * inv;
    __syncthreads();
    if (t < HD)
        out[(size_t)qi * DMODEL + h * HD + t] =
            sm.os[0][t] + sm.os[1][t] + sm.os[2][t] + sm.os[3][t];
    __syncthreads();
}

__device__ void dev_finish_norm(MegaShared& sm, int row, const float* Cp,
                                const float* res, const float* normw,
                                float* out_raw, float* out_norm, int nz) {
    int t = threadIdx.x;
    int c0 = t, c1 = t + 256;
    size_t base = (size_t)row * DMODEL;
    float v0 = 0.f, v1 = 0.f;
    for (int z = 0; z < nz; ++z) {
        size_t zb = (size_t)z * (NTOK * DMODEL) + base;
        v0 += Cp[zb + c0];
        v1 += Cp[zb + c1];
    }
    v0 += res[base + c0];
    v1 += res[base + c1];
    float ss = v0 * v0 + v1 * v1;
    int lane = t & 63, wv = t >> 6;
    for (int o = 32; o > 0; o >>= 1) ss += __shfl_xor(ss, o);
    if (lane == 0) sm.red[wv] = ss;
    __syncthreads();
    float tot = sm.red[0] + sm.red[1] + sm.red[2] + sm.red[3];
    float scale = rsqrtf(tot * (1.f / DMODEL) + EPSV);
    out_raw[base + c0] = v0;
    out_raw[base + c1] = v1;
    out_norm[base + c0] = v0 * scale * normw[c0];
    out_norm[base + c1] = v1 * scale * normw[c1];
    __syncthreads();
}

__device__ void dev_haltactab(MegaShared& sm, int i, const float* H,
                              const float* wh, const float* bptr,
                              float* ponder_out, float* w_out,
                              __hip_bfloat16* A, __hip_bfloat16* Bm) {
    int t = threadIdx.x;
    int lane = t & 63, wv = t >> 6;
    for (int s = 1; s <= 3; ++s) {
        const float* hr = H + ((size_t)s * NTOK + i) * DMODEL;
        float a = hr[t] * wh[t] + hr[t + 256] * wh[t + 256];
        for (int o = 32; o > 0; o >>= 1) a += __shfl_xor(a, o);
        if (lane == 0) sm.red[wv] = a;
        __syncthreads();
        if (t == 0)
            sm.hv[s - 1] = 1.f / (1.f + expf(-(sm.red[0] + sm.red[1] + sm.red[2] + sm.red[3] + bptr[0])));
        __syncthreads();
    }
    if (t == 0) {
        float p[4] = {0.f, sm.hv[0], sm.hv[1], sm.hv[2]};
        float cum = 0.f, rem = 0.f;
        int nrun = 0;
#pragma unroll
        for (int s = 0; s < 4; ++s) {
            float prev = cum;
            cum += p[s];
            bool running = prev < THR;
            bool use_rem = running && ((cum >= THR) || (s == 3));
            float v = 0.f;
            if (running) {
                v = use_rem ? (1.f - prev) : p[s];
                if (use_rem) rem += (1.f - prev);
                nrun++;
            }
            sm.hw[s] = v;
            w_out[i * 4 + s] = v;
        }
        ponder_out[i] = (float)nrun + rem;
    }
    __syncthreads();
    float w0 = sm.hw[0], w1 = sm.hw[1], w2 = sm.hw[2], w3 = sm.hw[3];
    size_t base = (size_t)i * DMODEL;
#pragma unroll
    for (int r = 0; r < 2; ++r) {
        int d = t + r * 256;
        float h0 = H[base + d];
        float h1 = H[(size_t)(NTOK * DMODEL) + base + d];
        float h2 = H[(size_t)(2 * NTOK * DMODEL) + base + d];
        float h3 = H[(size_t)(3 * NTOK * DMODEL) + base + d];
        float h4 = H[(size_t)(4 * NTOK * DMODEL) + base + d];
        A[base + d]  = __float2bfloat16(w0 * h0 + w1 * h1 + w2 * h2 + w3 * h3);
        Bm[base + d] = __float2bfloat16(w0 * h1 + w1 * h2 + w2 * h3 + w3 * h4);
    }
}

// ---------------- the mega kernel: everything except final logits ----------------
__global__ __launch_bounds__(256) void k_mega(
    const int* __restrict__ ids, const float* __restrict__ emb,
    const float* __restrict__ attn_norm_w, const float* __restrict__ mlp_norm_w,
    const float* __restrict__ wqkv, const float* __restrict__ wo,
    const float* __restrict__ w_gate, const float* __restrict__ w_up,
    const float* __restrict__ w_down, const float* __restrict__ final_norm_w,
    const float* __restrict__ rc_norm_w, const float* __restrict__ rc_w1,
    const float* __restrict__ rc_w2, const float* __restrict__ w_halt,
    const float* __restrict__ b_halt, float* __restrict__ out,
    float* __restrict__ ws_f, unsigned* __restrict__ bar) {
    __shared__ MegaShared sm;
    // workspace layout (identical to round 10, proven liveness)
    float* x       = ws_f + 0;
    float* xn      = ws_f + 131072;
    float* qkv     = ws_f + 262144;
    float* attnout = ws_f + 655360;
    float* g       = ws_f + 786432;
    float* t1      = ws_f + 1179648;
    float* states  = ws_f + 1703936;
    float* states2 = ws_f + 1835008;
    float* H       = ws_f + 1966080;
    __hip_bfloat16* Abf = (__hip_bfloat16*)(ws_f + 2623488);
    __hip_bfloat16* Bbf = (__hip_bfloat16*)(ws_f + 2754560);
    float* Cp      = ws_f + 2885632;
    float* GU      = ws_f + 1179648;
    unsigned* cnt = bar;
    unsigned* gen = bar + 1;
    const int b = blockIdx.x;

    // ---- embed + first norm ----
    dev_embed_norm(sm, b, ids, emb, attn_norm_w, x, xn);
    grid_bar(cnt, gen);

    for (int l = 0; l < NLAYER; ++l) {
        const float* Wq = wqkv + (size_t)l * DMODEL * FF;
        for (int t = b; t < 384; t += 256) {       // qkv: 24N x 4M x 4z, kc=128
            int nx = t % 24, my = (t / 24) & 3, z = t / 96;
            dev_mm_tile(sm, xn, Wq, Cp + (size_t)z * 256 * FF,
                        DMODEL, FF, 128, nx * 64, my * 64, z * 128);
        }
        grid_bar(cnt, gen);
        dev_qkv_rope(b, Cp, qkv);
        grid_bar(cnt, gen);
        for (int t = b; t < 2048; t += 256)        // attn: 8h x 256q
            dev_attn(sm, t & 7, t >> 3, qkv, attnout);
        grid_bar(cnt, gen);
        const float* Wo = wo + (size_t)l * DMODEL * DMODEL;
        for (int t = b; t < 256; t += 256) {       // wo: 8N x 4M x 8z, kc=64
            int nx = t % 8, my = (t / 8) & 3, z = t / 32;
            dev_mm_tile(sm, attnout, Wo, Cp + (size_t)z * 256 * DMODEL,
                        DMODEL, DMODEL, 64, nx * 64, my * 64, z * 64);
        }
        grid_bar(cnt, gen);
        dev_finish_norm(sm, b, Cp, x, mlp_norm_w + l * DMODEL, x, xn, 8);
        grid_bar(cnt, gen);
        const float* Wg = w_gate + (size_t)l * DMODEL * FF;
        const float* Wu = w_up + (size_t)l * DMODEL * FF;
        for (int t = b; t < 384; t += 256) {       // gate/up: 24N x 4M x 4z, kc=256
            int nx = t % 24, my = (t / 24) & 3, z = t / 96;
            dev_mm_tile(sm, xn, (z >> 1) ? Wu : Wg, GU + (size_t)z * 256 * FF,
                        DMODEL, FF, 256, nx * 64, my * 64, (z & 1) * 256);
        }
        grid_bar(cnt, gen);
        for (int i = b * 256 + threadIdx.x; i < NTOK * FF; i += 65536) {
            float gg = GU[i] + GU[(size_t)(NTOK * FF) + i];
            float uu = GU[(size_t)(2 * NTOK * FF) + i] + GU[(size_t)(3 * NTOK * FF) + i];
            g[i] = gg * (1.f / (1.f + expf(-gg))) * uu;
        }
        grid_bar(cnt, gen);
        const float* Wd = w_down + (size_t)l * FF * DMODEL;
        for (int t = b; t < 384; t += 256) {       // down: 8N x 4M x 12z, kc=128
            int nx = t % 8, my = (t / 8) & 3, z = t / 32;
            dev_mm_tile(sm, g, Wd, Cp + (size_t)z * 256 * DMODEL,
                        FF, DMODEL, 128, nx * 64, my * 64, z * 128);
        }
        grid_bar(cnt, gen);
        dev_finish_norm(sm, b, Cp, x,
                        (l == 0) ? (attn_norm_w + DMODEL) : final_norm_w,
                        x, (l == 0) ? xn : states, 12);
        grid_bar(cnt, gen);
    }

    // ---- refinement ----
    dev_rmsnorm(sm, b, states, rc_norm_w, H);
    grid_bar(cnt, gen);
    float* scur = states;
    float* snxt = states2;
    for (int s = 0; s < NSTEPS; ++s) {
        const float* Hs = H + (size_t)s * NTOK * DMODEL;
        for (int t = b; t < 512; t += 256) {       // w1: 32N x 4M x 4z, kc=128
            int nx = t % 32, my = (t / 32) & 3, z = t / 128;
            dev_mm_tile(sm, Hs, rc_w1, Cp + (size_t)z * 256 * RCFF,
                        DMODEL, RCFF, 128, nx * 64, my * 64, z * 128);
        }
        grid_bar(cnt, gen);
        for (int i = b * 256 + threadIdx.x; i < NTOK * RCFF; i += 65536) {
            float v = Cp[i] + Cp[(size_t)(NTOK * RCFF) + i]
                    + Cp[2 * (size_t)(NTOK * RCFF) + i] + Cp[3 * (size_t)(NTOK * RCFF) + i];
            float inner = 0.79788456080286536f * (v + 0.044715f * v * v * v);
            t1[i] = 0.5f * v * (1.f + tanhf(inner));
        }
        grid_bar(cnt, gen);
        for (int t = b; t < 512; t += 256) {       // w2: 8N x 4M x 16z, kc=128
            int nx = t % 8, my = (t / 8) & 3, z = t / 32;
            dev_mm_tile(sm, t1, rc_w2, Cp + (size_t)z * 256 * DMODEL,
                        RCFF, DMODEL, 128, nx * 64, my * 64, z * 128);
        }
        grid_bar(cnt, gen);
        dev_finish_norm(sm, b, Cp, scur, rc_norm_w, snxt,
                        H + (size_t)(s + 1) * NTOK * DMODEL, 16);
        grid_bar(cnt, gen);
        float* tmp = scur; scur = snxt; snxt = tmp;
    }

    // ---- halt + ACT + A/B ----
    dev_haltactab(sm, b, H, w_halt, b_halt,
                  out + (size_t)NTOK * VOCAB, out + (size_t)NTOK * VOCAB + NTOK,
                  Abf, Bbf);
}

// ---------------- final logits via MFMA (round-6 verbatim, 68us proven) -------
__global__ __launch_bounds__(512) void k_logits_mfma(const __hip_bfloat16* __restrict__ Abf,
                                                     const __hip_bfloat16* __restrict__ Bbf,
                                                     const float* __restrict__ Wy,
                                                     const float* __restrict__ Wd,
                                                     float* __restrict__ out) {
    __shared__ short Alds[256 * 32];
    __shared__ short Blds[256 * 32];
    __shared__ short Wys[32 * 70];
    __shared__ short Wds[32 * 70];
    const int tid  = threadIdx.x;
    const int wave = tid >> 6;
    const int lane = tid & 63;
    const int wrow = (wave & 1) * 128;
    const int wcol = (wave >> 1) * 16;
    const int cl   = lane & 15;
    const int kg   = lane >> 4;
    const int col  = blockIdx.x * 64 + wcol + cl;

    const int kr = tid >> 4;
    const int c4 = (tid & 15) * 4;
    const int sr0 = tid >> 2;
    const int skp = (tid & 3) * 8;

    f32x4 acc[8];
#pragma unroll
    for (int i = 0; i < 8; ++i) acc[i] = (f32x4){0.f, 0.f, 0.f, 0.f};

    const float* gy = Wy + (size_t)kr * VOCAB + blockIdx.x * 64 + c4;
    const float* gd = Wd + (size_t)kr * VOCAB + blockIdx.x * 64 + c4;

    float4 ry = *(const float4*)gy;
    float4 rd = *(const float4*)gd;
    bf16x8 ra0 = *(const bf16x8*)(Abf + (size_t)sr0 * DMODEL + skp);
    bf16x8 ra1 = *(const bf16x8*)(Abf + (size_t)(sr0 + 128) * DMODEL + skp);
    bf16x8 rb0 = *(const bf16x8*)(Bbf + (size_t)sr0 * DMODEL + skp);
    bf16x8 rb1 = *(const bf16x8*)(Bbf + (size_t)(sr0 + 128) * DMODEL + skp);

    for (int t = 0; t < 16; ++t) {
        __syncthreads();
        {
            short2 a, b;
            a.x = (short)__hip_bfloat16_raw(__float2bfloat16(ry.x)).x;
            a.y = (short)__hip_bfloat16_raw(__float2bfloat16(ry.y)).x;
            b.x = (short)__hip_bfloat16_raw(__float2bfloat16(ry.z)).x;
            b.y = (short)__hip_bfloat16_raw(__float2bfloat16(ry.w)).x;
            *(short2*)&Wys[kr * 70 + c4]     = a;
            *(short2*)&Wys[kr * 70 + c4 + 2] = b;
            a.x = (short)__hip_bfloat16_raw(__float2bfloat16(rd.x)).x;
            a.y = (short)__hip_bfloat16_raw(__float2bfloat16(rd.y)).x;
            b.x = (short)__hip_bfloat16_raw(__float2bfloat16(rd.z)).x;
            b.y = (short)__hip_bfloat16_raw(__float2bfloat16(rd.w)).x;
            *(short2*)&Wds[kr * 70 + c4]     = a;
            *(short2*)&Wds[kr * 70 + c4 + 2] = b;
            *(bf16x8*)&Alds[sr0 * 32 + skp]         = ra0;
            *(bf16x8*)&Alds[(sr0 + 128) * 32 + skp] = ra1;
            *(bf16x8*)&Blds[sr0 * 32 + skp]         = rb0;
            *(bf16x8*)&Blds[(sr0 + 128) * 32 + skp] = rb1;
        }
        if (t < 15) {
            const int kn = (t + 1) * 32;
            ry  = *(const float4*)(gy + (size_t)(t + 1) * 32 * VOCAB);
            rd  = *(const float4*)(gd + (size_t)(t + 1) * 32 * VOCAB);
            ra0 = *(const bf16x8*)(Abf + (size_t)sr0 * DMODEL + kn + skp);
            ra1 = *(const bf16x8*)(Abf + (size_t)(sr0 + 128) * DMODEL + kn + skp);
            rb0 = *(const bf16x8*)(Bbf + (size_t)sr0 * DMODEL + kn + skp);
            rb1 = *(const bf16x8*)(Bbf + (size_t)(sr0 + 128) * DMODEL + kn + skp);
        }
        __syncthreads();
        bf16x8 wy, wd;
#pragma unroll
        for (int j = 0; j < 8; ++j) {
            wy[j] = Wys[(kg * 8 + j) * 70 + wcol + cl];
            wd[j] = Wds[(kg * 8 + j) * 70 + wcol + cl];
        }
#pragma unroll
        for (int mt = 0; mt < 8; ++mt) {
            const int row = wrow + mt * 16 + cl;
            const bf16x8 a = *(const bf16x8*)&Alds[row * 32 + kg * 8];
            const bf16x8 bb = *(const bf16x8*)&Blds[row * 32 + kg * 8];
            acc[mt] = __builtin_amdgcn_mfma_f32_16x16x32_bf16(a, wy, acc[mt], 0, 0, 0);
            acc[mt] = __builtin_amdgcn_mfma_f32_16x16x32_bf16(bb, wd, acc[mt], 0, 0, 0);
        }
    }
#pragma unroll
    for (int mt = 0; mt < 8; ++mt)
#pragma unroll
        for (int r = 0; r < 4; ++r)
            out[(size_t)(wrow + mt * 16 + kg * 4 + r) * VOCAB + col] = acc[mt][r];
}

extern "C" void kernel_launch(void* const* d_in, const int* in_sizes, int n_in,
                              void* d_out, int out_size, void* d_ws, size_t ws_size,
                              hipStream_t stream) {
    const int*   ids          = (const int*)d_in[0];
    const float* emb          = (const float*)d_in[1];
    const float* attn_norm_w  = (const float*)d_in[2];
    const float* mlp_norm_w   = (const float*)d_in[3];
    const float* wqkv         = (const float*)d_in[4];
    const float* wo           = (const float*)d_in[5];
    const float* w_gate       = (const float*)d_in[6];
    const float* w_up         = (const float*)d_in[7];
    const float* w_down       = (const float*)d_in[8];
    const float* final_norm_w = (const float*)d_in[9];
    const float* rc_norm_w    = (const float*)d_in[10];
    const float* rc_w1        = (const float*)d_in[11];
    const float* rc_w2        = (const float*)d_in[12];
    const float* w_y          = (const float*)d_in[13];
    const float* w_delta      = (const float*)d_in[14];
    const float* w_halt       = (const float*)d_in[15];
    const float* b_halt       = (const float*)d_in[16];
    float* out = (float*)d_out;

    float* ws = (float*)d_ws;
    __hip_bfloat16* Abf = (__hip_bfloat16*)(ws + 2623488);
    __hip_bfloat16* Bbf = (__hip_bfloat16*)(ws + 2754560);
    unsigned* bar = (unsigned*)(ws + 4982784);   // just past Cp end; untouched by stages

    k_barinit<<<1, 1, 0, stream>>>(bar);
    k_mega<<<256, 256, 0, stream>>>(ids, emb, attn_norm_w, mlp_norm_w, wqkv, wo,
                                    w_gate, w_up, w_down, final_norm_w, rc_norm_w,
                                    rc_w1, rc_w2, w_halt, b_halt, out, ws, bar);
    k_logits_mfma<<<VOCAB / 64, 512, 0, stream>>>(Abf, Bbf, w_y, w_delta, out);
}

// Round 12
// 374.812 us; speedup vs baseline: 8.8518x; 8.8518x over previous
//
#include <hip/hip_runtime.h>
#include <hip/hip_bf16.h>

#define NTOK   256
#define DMODEL 512
#define NHEAD  8
#define HD     64
#define HALF   32
#define FF     1536
#define RCFF   2048
#define VOCAB  32000
#define NLAYER 2
#define NSTEPS 4
#define EPSV   1e-6f
#define THR    0.99f

typedef __attribute__((ext_vector_type(8))) short bf16x8;
typedef __attribute__((ext_vector_type(4))) float f32x4;

// ---------------- embedding gather + first rmsnorm fused ----------------
__global__ __launch_bounds__(256) void k_embed_norm(const int* __restrict__ ids,
                                                    const float* __restrict__ emb,
                                                    const float* __restrict__ w,
                                                    float* __restrict__ x,
                                                    float* __restrict__ xn) {
    int row = blockIdx.x, t = threadIdx.x;
    int id = ids[row];
    const float* er = emb + (size_t)id * DMODEL;
    float v0 = er[t], v1 = er[t + 256];
    float ss = v0 * v0 + v1 * v1;
    __shared__ float red[4];
    int lane = t & 63, wv = t >> 6;
    for (int o = 32; o > 0; o >>= 1) ss += __shfl_xor(ss, o);
    if (lane == 0) red[wv] = ss;
    __syncthreads();
    float tot = red[0] + red[1] + red[2] + red[3];
    float scale = rsqrtf(tot * (1.f / DMODEL) + EPSV);
    size_t base = (size_t)row * DMODEL;
    x[base + t] = v0;
    x[base + t + 256] = v1;
    xn[base + t] = v0 * scale * w[t];
    xn[base + t + 256] = v1 * scale * w[t + 256];
}

// ---------------- rmsnorm (one block per row) ----------------
__global__ __launch_bounds__(256) void k_rmsnorm(const float* __restrict__ in,
                                                 const float* __restrict__ w,
                                                 float* __restrict__ out) {
    int row = blockIdx.x;
    const float* xr = in + (size_t)row * DMODEL;
    float s = 0.f;
    for (int d = threadIdx.x; d < DMODEL; d += 256) { float v = xr[d]; s += v * v; }
    __shared__ float red[4];
    int lane = threadIdx.x & 63, wv = threadIdx.x >> 6;
    for (int o = 32; o > 0; o >>= 1) s += __shfl_xor(s, o);
    if (lane == 0) red[wv] = s;
    __syncthreads();
    float tot = red[0] + red[1] + red[2] + red[3];
    float scale = rsqrtf(tot * (1.f / DMODEL) + EPSV);
    for (int d = threadIdx.x; d < DMODEL; d += 256)
        out[(size_t)row * DMODEL + d] = xr[d] * scale * w[d];
}

// ---------------- split-K matmul partial (64x64 tile + register prefetch) ------
// Same math/order as the round-6 kernel; chunk t+1's global loads are issued
// right after the store barrier so their latency hides under the FMA phase.
__global__ __launch_bounds__(256) void k_mm_part(const float* __restrict__ A,
                                                 const float* __restrict__ W,
                                                 float* __restrict__ Cp,
                                                 int K, int N, int kc) {
    __shared__ float As[16][68];
    __shared__ float Ws[16][68];
    const int bn = blockIdx.x * 64;
    const int bm = blockIdx.y * 64;
    const int kz = blockIdx.z * kc;
    const int tx = threadIdx.x & 15;
    const int ty = threadIdx.x >> 4;
    float ar[4], wr[4];
#pragma unroll
    for (int r = 0; r < 4; ++r) {
        int idx = threadIdx.x + r * 256;
        int m = idx >> 4, kk = idx & 15;
        ar[r] = A[(size_t)(bm + m) * K + kz + kk];
        int n = idx & 63, kw = idx >> 6;
        wr[r] = W[(size_t)(kz + kw) * N + bn + n];
    }
    float acc[4][4] = {};
    for (int k0 = kz; k0 < kz + kc; k0 += 16) {
#pragma unroll
        for (int r = 0; r < 4; ++r) {
            int idx = threadIdx.x + r * 256;
            int m = idx >> 4, kk = idx & 15;
            As[kk][m] = ar[r];
            int n = idx & 63, kw = idx >> 6;
            Ws[kw][n] = wr[r];
        }
        __syncthreads();
        if (k0 + 16 < kz + kc) {   // prefetch next chunk into registers
#pragma unroll
            for (int r = 0; r < 4; ++r) {
                int idx = threadIdx.x + r * 256;
                int m = idx >> 4, kk = idx & 15;
                ar[r] = A[(size_t)(bm + m) * K + k0 + 16 + kk];
                int n = idx & 63, kw = idx >> 6;
                wr[r] = W[(size_t)(k0 + 16 + kw) * N + bn + n];
            }
        }
#pragma unroll
        for (int kk = 0; kk < 16; ++kk) {
            float4 av = *(const float4*)&As[kk][ty * 4];
            float4 bv = *(const float4*)&Ws[kk][tx * 4];
            float a[4] = {av.x, av.y, av.z, av.w};
            float b[4] = {bv.x, bv.y, bv.z, bv.w};
#pragma unroll
            for (int i = 0; i < 4; ++i)
#pragma unroll
                for (int j = 0; j < 4; ++j)
                    acc[i][j] = fmaf(a[i], b[j], acc[i][j]);
        }
        __syncthreads();
    }
    float* cp = Cp + (size_t)blockIdx.z * (size_t)(gridDim.y * 64) * N;
#pragma unroll
    for (int i = 0; i < 4; ++i) {
        int m = bm + ty * 4 + i;
#pragma unroll
        for (int j = 0; j < 4; ++j)
            cp[(size_t)m * N + bn + tx * 4 + j] = acc[i][j];
    }
}

// ---------------- gate+up combined split-K partial: 4 slices + prefetch --------
// z = 0..3: z>>1 selects gate(0)/up(1); z&1 selects the 256-wide k chunk.
__global__ __launch_bounds__(256) void k_gu_part(const float* __restrict__ A,
                                                 const float* __restrict__ Wg,
                                                 const float* __restrict__ Wu,
                                                 float* __restrict__ GU) {
    __shared__ float As[16][68];
    __shared__ float Ws[16][68];
    const int bn = blockIdx.x * 64;
    const int bm = blockIdx.y * 64;
    const int z = blockIdx.z;
    const float* W = (z >> 1) ? Wu : Wg;
    const int kz = (z & 1) * 256;
    const int tx = threadIdx.x & 15;
    const int ty = threadIdx.x >> 4;
    float ar[4], wr[4];
#pragma unroll
    for (int r = 0; r < 4; ++r) {
        int idx = threadIdx.x + r * 256;
        int m = idx >> 4, kk = idx & 15;
        ar[r] = A[(size_t)(bm + m) * DMODEL + kz + kk];
        int n = idx & 63, kw = idx >> 6;
        wr[r] = W[(size_t)(kz + kw) * FF + bn + n];
    }
    float acc[4][4] = {};
    for (int k0 = kz; k0 < kz + 256; k0 += 16) {
#pragma unroll
        for (int r = 0; r < 4; ++r) {
            int idx = threadIdx.x + r * 256;
            int m = idx >> 4, kk = idx & 15;
            As[kk][m] = ar[r];
            int n = idx & 63, kw = idx >> 6;
            Ws[kw][n] = wr[r];
        }
        __syncthreads();
        if (k0 + 16 < kz + 256) {
#pragma unroll
            for (int r = 0; r < 4; ++r) {
                int idx = threadIdx.x + r * 256;
                int m = idx >> 4, kk = idx & 15;
                ar[r] = A[(size_t)(bm + m) * DMODEL + k0 + 16 + kk];
                int n = idx & 63, kw = idx >> 6;
                wr[r] = W[(size_t)(k0 + 16 + kw) * FF + bn + n];
            }
        }
#pragma unroll
        for (int kk = 0; kk < 16; ++kk) {
            float4 av = *(const float4*)&As[kk][ty * 4];
            float4 bv = *(const float4*)&Ws[kk][tx * 4];
            float a[4] = {av.x, av.y, av.z, av.w};
            float b[4] = {bv.x, bv.y, bv.z, bv.w};
#pragma unroll
            for (int i = 0; i < 4; ++i)
#pragma unroll
                for (int j = 0; j < 4; ++j)
                    acc[i][j] = fmaf(a[i], b[j], acc[i][j]);
        }
        __syncthreads();
    }
    float* cp = GU + (size_t)z * (NTOK * FF);
#pragma unroll
    for (int i = 0; i < 4; ++i) {
        int m = bm + ty * 4 + i;
#pragma unroll
        for (int j = 0; j < 4; ++j)
            cp[(size_t)m * FF + bn + tx * 4 + j] = acc[i][j];
    }
}

// ---------------- split-K elementwise reduce (+optional gelu) ----------------
__global__ void k_mm_finish(const float* __restrict__ Cp, const float* __restrict__ res,
                            float* __restrict__ C, int tot, int zstride, int nz, int act) {
    int i = blockIdx.x * 256 + threadIdx.x;
    if (i >= tot) return;
    float s = 0.f;
    for (int z = 0; z < nz; ++z) s += Cp[(size_t)z * zstride + i];
    if (res) s += res[i];
    if (act == 1) {  // gelu (tanh approx, jax default)
        float xg = s;
        float inner = 0.79788456080286536f * (xg + 0.044715f * xg * xg * xg);
        s = 0.5f * xg * (1.f + tanhf(inner));
    }
    C[i] = s;
}

// ---------------- reduce + silu(g)*u  (gate z=0..1, up z=2..3) ----------------
__global__ void k_finish_silumul(const float* __restrict__ GU, float* __restrict__ C) {
    int i = blockIdx.x * 256 + threadIdx.x;   // tot = 256*1536
    float g = GU[i] + GU[(size_t)(NTOK * FF) + i];
    float u = GU[(size_t)(2 * NTOK * FF) + i] + GU[(size_t)(3 * NTOK * FF) + i];
    float sig = 1.f / (1.f + expf(-g));
    C[i] = g * sig * u;
}

// ---------------- reduce + residual + dual write (raw, rmsnorm) ----------------
__global__ __launch_bounds__(256) void k_finish_norm(const float* __restrict__ Cp,
                                                     const float* __restrict__ res,
                                                     const float* __restrict__ normw,
                                                     float* __restrict__ out_raw,
                                                     float* __restrict__ out_norm,
                                                     int nz) {
    int row = blockIdx.x, t = threadIdx.x;
    int c0 = t, c1 = t + 256;
    size_t base = (size_t)row * DMODEL;
    float v0 = 0.f, v1 = 0.f;
    for (int z = 0; z < nz; ++z) {
        size_t zb = (size_t)z * (NTOK * DMODEL) + base;
        v0 += Cp[zb + c0];
        v1 += Cp[zb + c1];
    }
    v0 += res[base + c0];
    v1 += res[base + c1];
    float ss = v0 * v0 + v1 * v1;
    __shared__ float red[4];
    int lane = t & 63, wv = t >> 6;
    for (int o = 32; o > 0; o >>= 1) ss += __shfl_xor(ss, o);
    if (lane == 0) red[wv] = ss;
    __syncthreads();
    float tot = red[0] + red[1] + red[2] + red[3];
    float scale = rsqrtf(tot * (1.f / DMODEL) + EPSV);
    out_raw[base + c0] = v0;
    out_raw[base + c1] = v1;
    out_norm[base + c0] = v0 * scale * normw[c0];
    out_norm[base + c1] = v1 * scale * normw[c1];
}

// ---------------- qkv reduce + RoPE fused (z=4 slices, N=1536) ----------------
__global__ __launch_bounds__(256) void k_qkv_finish_rope(const float* __restrict__ Cp,
                                                         float* __restrict__ qkv) {
    int pos = blockIdx.x, t = threadIdx.x;
    int h = t >> 5, d = t & 31;
    size_t base = (size_t)pos * FF;
    auto S = [&](int col) {
        float s = 0.f;
#pragma unroll
        for (int z = 0; z < 4; ++z) s += Cp[(size_t)z * (NTOK * FF) + base + col];
        return s;
    };
    int cq0 = h * HD + d, cq1 = cq0 + HALF;
    int ck0 = DMODEL + cq0, ck1 = ck0 + HALF;
    int cv0 = 2 * DMODEL + t, cv1 = cv0 + 256;
    float q0 = S(cq0), q1 = S(cq1);
    float k0 = S(ck0), k1 = S(ck1);
    float v0 = S(cv0), v1 = S(cv1);
    float inv = powf(10000.f, -(float)d / 32.f);
    float ang = (float)pos * inv;
    float c = cosf(ang), s = sinf(ang);
    qkv[base + cq0] = q0 * c - q1 * s;
    qkv[base + cq1] = q0 * s + q1 * c;
    qkv[base + ck0] = k0 * c - k1 * s;
    qkv[base + ck1] = k0 * s + k1 * c;
    qkv[base + cv0] = v0;
    qkv[base + cv1] = v1;
}

// ---------------- attention: one block per (head, query) ----------------
__global__ __launch_bounds__(256) void k_attn(const float* __restrict__ qkv,
                                              float* __restrict__ out) {
    int h = blockIdx.x;
    int qi = blockIdx.y;
    int t = threadIdx.x;
    __shared__ float qs[HD];
    __shared__ float ps[NTOK];
    __shared__ float red[4];
    __shared__ float red2[4];
    __shared__ float os[4][HD];
    if (t < HD) qs[t] = qkv[(size_t)qi * FF + h * HD + t];
    __syncthreads();
    float sc = -1e30f;
    if (t <= qi) {
        const float* kr = qkv + (size_t)t * FF + DMODEL + h * HD;
        float s = 0.f;
        for (int d = 0; d < HD; ++d) s = fmaf(qs[d], kr[d], s);
        sc = s * 0.125f;
    }
    float m = sc;
    for (int o = 32; o > 0; o >>= 1) m = fmaxf(m, __shfl_xor(m, o));
    int lane = t & 63, wv = t >> 6;
    if (lane == 0) red[wv] = m;
    __syncthreads();
    m = fmaxf(fmaxf(red[0], red[1]), fmaxf(red[2], red[3]));
    float e = (t <= qi) ? expf(sc - m) : 0.f;
    ps[t] = e;
    float sum = e;
    for (int o = 32; o > 0; o >>= 1) sum += __shfl_xor(sum, o);
    if (lane == 0) red2[wv] = sum;
    __syncthreads();
    sum = red2[0] + red2[1] + red2[2] + red2[3];
    float inv = 1.f / sum;
    int d = t & 63, g = t >> 6;
    float acc = 0.f;
    for (int ki = g; ki <= qi; ki += 4)
        acc = fmaf(ps[ki], qkv[(size_t)ki * FF + 2 * DMODEL + h * HD + d], acc);
    os[g][d] = acc * inv;
    __syncthreads();
    if (t < HD)
        out[(size_t)qi * DMODEL + h * HD + t] = os[0][t] + os[1][t] + os[2][t] + os[3][t];
}

// ---------------- halt dots + ACT combine + A/B build, one block per token ----
__global__ __launch_bounds__(256) void k_haltactab(const float* __restrict__ H,
                                                   const float* __restrict__ wh,
                                                   const float* __restrict__ bptr,
                                                   float* __restrict__ ponder_out,
                                                   float* __restrict__ w_out,
                                                   __hip_bfloat16* __restrict__ A,
                                                   __hip_bfloat16* __restrict__ Bm) {
    int i = blockIdx.x, t = threadIdx.x;
    int lane = t & 63, wv = t >> 6;
    __shared__ float red[4];
    __shared__ float hvals[3];
    __shared__ float hw[4];
    for (int s = 1; s <= 3; ++s) {
        const float* hr = H + ((size_t)s * NTOK + i) * DMODEL;
        float a = hr[t] * wh[t] + hr[t + 256] * wh[t + 256];
        for (int o = 32; o > 0; o >>= 1) a += __shfl_xor(a, o);
        if (lane == 0) red[wv] = a;
        __syncthreads();
        if (t == 0)
            hvals[s - 1] = 1.f / (1.f + expf(-(red[0] + red[1] + red[2] + red[3] + bptr[0])));
        __syncthreads();
    }
    if (t == 0) {
        float p[4] = {0.f, hvals[0], hvals[1], hvals[2]};
        float cum = 0.f, rem = 0.f;
        int nrun = 0;
#pragma unroll
        for (int s = 0; s < 4; ++s) {
            float prev = cum;
            cum += p[s];
            bool running = prev < THR;
            bool use_rem = running && ((cum >= THR) || (s == 3));
            float v = 0.f;
            if (running) {
                v = use_rem ? (1.f - prev) : p[s];
                if (use_rem) rem += (1.f - prev);
                nrun++;
            }
            hw[s] = v;
            w_out[i * 4 + s] = v;
        }
        ponder_out[i] = (float)nrun + rem;
    }
    __syncthreads();
    float w0 = hw[0], w1 = hw[1], w2 = hw[2], w3 = hw[3];
    size_t base = (size_t)i * DMODEL;
#pragma unroll
    for (int r = 0; r < 2; ++r) {
        int d = t + r * 256;
        float h0 = H[base + d];
        float h1 = H[(size_t)(NTOK * DMODEL) + base + d];
        float h2 = H[(size_t)(2 * NTOK * DMODEL) + base + d];
        float h3 = H[(size_t)(3 * NTOK * DMODEL) + base + d];
        float h4 = H[(size_t)(4 * NTOK * DMODEL) + base + d];
        A[base + d]  = __float2bfloat16(w0 * h0 + w1 * h1 + w2 * h2 + w3 * h3);
        Bm[base + d] = __float2bfloat16(w0 * h1 + w1 * h2 + w2 * h3 + w3 * h4);
    }
}

// ---------------- final logits via MFMA (round-6 verbatim, 68us proven) -------
__global__ __launch_bounds__(512) void k_logits_mfma(const __hip_bfloat16* __restrict__ Abf,
                                                     const __hip_bfloat16* __restrict__ Bbf,
                                                     const float* __restrict__ Wy,
                                                     const float* __restrict__ Wd,
                                                     float* __restrict__ out) {
    __shared__ short Alds[256 * 32];
    __shared__ short Blds[256 * 32];
    __shared__ short Wys[32 * 70];
    __shared__ short Wds[32 * 70];
    const int tid  = threadIdx.x;
    const int wave = tid >> 6;
    const int lane = tid & 63;
    const int wrow = (wave & 1) * 128;
    const int wcol = (wave >> 1) * 16;
    const int cl   = lane & 15;
    const int kg   = lane >> 4;
    const int col  = blockIdx.x * 64 + wcol + cl;

    const int kr = tid >> 4;
    const int c4 = (tid & 15) * 4;
    const int sr0 = tid >> 2;
    const int skp = (tid & 3) * 8;

    f32x4 acc[8];
#pragma unroll
    for (int i = 0; i < 8; ++i) acc[i] = (f32x4){0.f, 0.f, 0.f, 0.f};

    const float* gy = Wy + (size_t)kr * VOCAB + blockIdx.x * 64 + c4;
    const float* gd = Wd + (size_t)kr * VOCAB + blockIdx.x * 64 + c4;

    float4 ry = *(const float4*)gy;
    float4 rd = *(const float4*)gd;
    bf16x8 ra0 = *(const bf16x8*)(Abf + (size_t)sr0 * DMODEL + skp);
    bf16x8 ra1 = *(const bf16x8*)(Abf + (size_t)(sr0 + 128) * DMODEL + skp);
    bf16x8 rb0 = *(const bf16x8*)(Bbf + (size_t)sr0 * DMODEL + skp);
    bf16x8 rb1 = *(const bf16x8*)(Bbf + (size_t)(sr0 + 128) * DMODEL + skp);

    for (int t = 0; t < 16; ++t) {
        __syncthreads();
        {
            short2 a, b;
            a.x = (short)__hip_bfloat16_raw(__float2bfloat16(ry.x)).x;
            a.y = (short)__hip_bfloat16_raw(__float2bfloat16(ry.y)).x;
            b.x = (short)__hip_bfloat16_raw(__float2bfloat16(ry.z)).x;
            b.y = (short)__hip_bfloat16_raw(__float2bfloat16(ry.w)).x;
            *(short2*)&Wys[kr * 70 + c4]     = a;
            *(short2*)&Wys[kr * 70 + c4 + 2] = b;
            a.x = (short)__hip_bfloat16_raw(__float2bfloat16(rd.x)).x;
            a.y = (short)__hip_bfloat16_raw(__float2bfloat16(rd.y)).x;
            b.x = (short)__hip_bfloat16_raw(__float2bfloat16(rd.z)).x;
            b.y = (short)__hip_bfloat16_raw(__float2bfloat16(rd.w)).x;
            *(short2*)&Wds[kr * 70 + c4]     = a;
            *(short2*)&Wds[kr * 70 + c4 + 2] = b;
            *(bf16x8*)&Alds[sr0 * 32 + skp]         = ra0;
            *(bf16x8*)&Alds[(sr0 + 128) * 32 + skp] = ra1;
            *(bf16x8*)&Blds[sr0 * 32 + skp]         = rb0;
            *(bf16x8*)&Blds[(sr0 + 128) * 32 + skp] = rb1;
        }
        if (t < 15) {
            const int kn = (t + 1) * 32;
            ry  = *(const float4*)(gy + (size_t)(t + 1) * 32 * VOCAB);
            rd  = *(const float4*)(gd + (size_t)(t + 1) * 32 * VOCAB);
            ra0 = *(const bf16x8*)(Abf + (size_t)sr0 * DMODEL + kn + skp);
            ra1 = *(const bf16x8*)(Abf + (size_t)(sr0 + 128) * DMODEL + kn + skp);
            rb0 = *(const bf16x8*)(Bbf + (size_t)sr0 * DMODEL + kn + skp);
            rb1 = *(const bf16x8*)(Bbf + (size_t)(sr0 + 128) * DMODEL + kn + skp);
        }
        __syncthreads();
        bf16x8 wy, wd;
#pragma unroll
        for (int j = 0; j < 8; ++j) {
            wy[j] = Wys[(kg * 8 + j) * 70 + wcol + cl];
            wd[j] = Wds[(kg * 8 + j) * 70 + wcol + cl];
        }
#pragma unroll
        for (int mt = 0; mt < 8; ++mt) {
            const int row = wrow + mt * 16 + cl;
            const bf16x8 a = *(const bf16x8*)&Alds[row * 32 + kg * 8];
            const bf16x8 bb = *(const bf16x8*)&Blds[row * 32 + kg * 8];
            acc[mt] = __builtin_amdgcn_mfma_f32_16x16x32_bf16(a, wy, acc[mt], 0, 0, 0);
            acc[mt] = __builtin_amdgcn_mfma_f32_16x16x32_bf16(bb, wd, acc[mt], 0, 0, 0);
        }
    }
#pragma unroll
    for (int mt = 0; mt < 8; ++mt)
#pragma unroll
        for (int r = 0; r < 4; ++r)
            out[(size_t)(wrow + mt * 16 + kg * 4 + r) * VOCAB + col] = acc[mt][r];
}

extern "C" void kernel_launch(void* const* d_in, const int* in_sizes, int n_in,
                              void* d_out, int out_size, void* d_ws, size_t ws_size,
                              hipStream_t stream) {
    const int*   ids          = (const int*)d_in[0];
    const float* emb          = (const float*)d_in[1];
    const float* attn_norm_w  = (const float*)d_in[2];
    const float* mlp_norm_w   = (const float*)d_in[3];
    const float* wqkv         = (const float*)d_in[4];
    const float* wo           = (const float*)d_in[5];
    const float* w_gate       = (const float*)d_in[6];
    const float* w_up         = (const float*)d_in[7];
    const float* w_down       = (const float*)d_in[8];
    const float* final_norm_w = (const float*)d_in[9];
    const float* rc_norm_w    = (const float*)d_in[10];
    const float* rc_w1        = (const float*)d_in[11];
    const float* rc_w2        = (const float*)d_in[12];
    const float* w_y          = (const float*)d_in[13];
    const float* w_delta      = (const float*)d_in[14];
    const float* w_halt       = (const float*)d_in[15];
    const float* b_halt       = (const float*)d_in[16];
    float* out = (float*)d_out;

    float* ws = (float*)d_ws;
    // Live-range map (floats) — identical to round 10 (proven):
    //   x 0.. | xn 131072.. | qkv 262144.. | attnout 655360.. | g 786432..
    //   t1 1179648.. | states 1703936.. | states2 1835008.. | H 1966080..
    //   Abf 2623488.. | Bbf 2754560.. | Cp 2885632.. | GU 1179648.. (backbone only)
    float* x       = ws + 0;
    float* xn      = ws + 131072;
    float* qkv     = ws + 262144;
    float* attnout = ws + 655360;
    float* g       = ws + 786432;
    float* t1      = ws + 1179648;
    float* states  = ws + 1703936;
    float* states2 = ws + 1835008;
    float* H       = ws + 1966080;
    __hip_bfloat16* Abf = (__hip_bfloat16*)(ws + 2623488);
    __hip_bfloat16* Bbf = (__hip_bfloat16*)(ws + 2754560);
    float* Cp      = ws + 2885632;
    float* GU      = ws + 1179648;

    // ---------- backbone ----------
    k_embed_norm<<<NTOK, 256, 0, stream>>>(ids, emb, attn_norm_w, x, xn);
    for (int l = 0; l < NLAYER; ++l) {
        // qkv: K=512 N=1536, split 4 -> Cp; finish fused with RoPE
        k_mm_part<<<dim3(FF / 64, 4, 4), 256, 0, stream>>>(
            xn, wqkv + (size_t)l * DMODEL * FF, Cp, DMODEL, FF, 128);
        k_qkv_finish_rope<<<NTOK, 256, 0, stream>>>(Cp, qkv);
        k_attn<<<dim3(NHEAD, NTOK), 256, 0, stream>>>(qkv, attnout);
        // wo: K=512 N=512, split 8 -> Cp; finish fused with rmsnorm(mlp_norm)
        k_mm_part<<<dim3(DMODEL / 64, 4, 8), 256, 0, stream>>>(
            attnout, wo + (size_t)l * DMODEL * DMODEL, Cp, DMODEL, DMODEL, 64);
        k_finish_norm<<<NTOK, 256, 0, stream>>>(Cp, x, mlp_norm_w + l * DMODEL, x, xn, 8);
        // gate+up: one launch, 4 slices -> GU; reduce+silu*u -> g
        k_gu_part<<<dim3(FF / 64, 4, 4), 256, 0, stream>>>(
            xn, w_gate + (size_t)l * DMODEL * FF, w_up + (size_t)l * DMODEL * FF, GU);
        k_finish_silumul<<<NTOK * FF / 256, 256, 0, stream>>>(GU, g);
        // down: K=1536 N=512, split 12 -> Cp; finish fused with next norm
        k_mm_part<<<dim3(DMODEL / 64, 4, 12), 256, 0, stream>>>(
            g, w_down + (size_t)l * FF * DMODEL, Cp, FF, DMODEL, 128);
        const float* nw = (l == 0) ? (attn_norm_w + DMODEL) : final_norm_w;
        float* nout = (l == 0) ? xn : states;
        k_finish_norm<<<NTOK, 256, 0, stream>>>(Cp, x, nw, x, nout, 12);
    }

    // ---------- refinement steps (halt path stays f32) ----------
    k_rmsnorm<<<NTOK, 256, 0, stream>>>(states, rc_norm_w, H);
    float* scur = states;
    float* snxt = states2;
    for (int s = 0; s < NSTEPS; ++s) {
        // w1: K=512 N=2048, split 4 -> Cp; gelu in elementwise finish -> t1
        k_mm_part<<<dim3(RCFF / 64, 4, 4), 256, 0, stream>>>(
            H + (size_t)s * NTOK * DMODEL, rc_w1, Cp, DMODEL, RCFF, 128);
        k_mm_finish<<<NTOK * RCFF / 256, 256, 0, stream>>>(
            Cp, nullptr, t1, NTOK * RCFF, NTOK * RCFF, 4, 1);
        // w2: K=2048 N=512, split 16 -> Cp; finish fused residual+rmsnorm -> H_{s+1}
        k_mm_part<<<dim3(DMODEL / 64, 4, 16), 256, 0, stream>>>(
            t1, rc_w2, Cp, RCFF, DMODEL, 128);
        k_finish_norm<<<NTOK, 256, 0, stream>>>(
            Cp, scur, rc_norm_w, snxt, H + (size_t)(s + 1) * NTOK * DMODEL, 16);
        float* tmp = scur; scur = snxt; snxt = tmp;
    }

    // ---------- halt + ACT + A/B in one kernel ----------
    k_haltactab<<<NTOK, 256, 0, stream>>>(H, w_halt, b_halt,
                                          out + (size_t)NTOK * VOCAB,
                                          out + (size_t)NTOK * VOCAB + NTOK,
                                          Abf, Bbf);

    // ---------- final logits (MFMA bf16, LDS-staged, round-6 layout) ----------
    k_logits_mfma<<<VOCAB / 64, 512, 0, stream>>>(Abf, Bbf, w_y, w_delta, out);
}

// Round 13
// 372.232 us; speedup vs baseline: 8.9131x; 1.0069x over previous
//
#include <hip/hip_runtime.h>
#include <hip/hip_bf16.h>

#define NTOK   256
#define DMODEL 512
#define NHEAD  8
#define HD     64
#define HALF   32
#define FF     1536
#define RCFF   2048
#define VOCAB  32000
#define NLAYER 2
#define NSTEPS 4
#define EPSV   1e-6f
#define THR    0.99f

typedef __attribute__((ext_vector_type(8))) short bf16x8;
typedef __attribute__((ext_vector_type(4))) float f32x4;
typedef __attribute__((ext_vector_type(16))) float f32x16;

__device__ __forceinline__ short f2b(float x) {
    return (short)__hip_bfloat16_raw(__float2bfloat16(x)).x;
}

// ---------------- embedding gather + first rmsnorm fused ----------------
__global__ __launch_bounds__(256) void k_embed_norm(const int* __restrict__ ids,
                                                    const float* __restrict__ emb,
                                                    const float* __restrict__ w,
                                                    float* __restrict__ x,
                                                    float* __restrict__ xn) {
    int row = blockIdx.x, t = threadIdx.x;
    int id = ids[row];
    const float* er = emb + (size_t)id * DMODEL;
    float v0 = er[t], v1 = er[t + 256];
    float ss = v0 * v0 + v1 * v1;
    __shared__ float red[4];
    int lane = t & 63, wv = t >> 6;
    for (int o = 32; o > 0; o >>= 1) ss += __shfl_xor(ss, o);
    if (lane == 0) red[wv] = ss;
    __syncthreads();
    float tot = red[0] + red[1] + red[2] + red[3];
    float scale = rsqrtf(tot * (1.f / DMODEL) + EPSV);
    size_t base = (size_t)row * DMODEL;
    x[base + t] = v0;
    x[base + t + 256] = v1;
    xn[base + t] = v0 * scale * w[t];
    xn[base + t + 256] = v1 * scale * w[t + 256];
}

// ---------------- rmsnorm (one block per row) ----------------
__global__ __launch_bounds__(256) void k_rmsnorm(const float* __restrict__ in,
                                                 const float* __restrict__ w,
                                                 float* __restrict__ out) {
    int row = blockIdx.x;
    const float* xr = in + (size_t)row * DMODEL;
    float s = 0.f;
    for (int d = threadIdx.x; d < DMODEL; d += 256) { float v = xr[d]; s += v * v; }
    __shared__ float red[4];
    int lane = threadIdx.x & 63, wv = threadIdx.x >> 6;
    for (int o = 32; o > 0; o >>= 1) s += __shfl_xor(s, o);
    if (lane == 0) red[wv] = s;
    __syncthreads();
    float tot = red[0] + red[1] + red[2] + red[3];
    float scale = rsqrtf(tot * (1.f / DMODEL) + EPSV);
    for (int d = threadIdx.x; d < DMODEL; d += 256)
        out[(size_t)row * DMODEL + d] = xr[d] * scale * w[d];
}

// ---------------- split-K matmul partial (64x64 tile + register prefetch) ------
__global__ __launch_bounds__(256) void k_mm_part(const float* __restrict__ A,
                                                 const float* __restrict__ W,
                                                 float* __restrict__ Cp,
                                                 int K, int N, int kc) {
    __shared__ float As[16][68];
    __shared__ float Ws[16][68];
    const int bn = blockIdx.x * 64;
    const int bm = blockIdx.y * 64;
    const int kz = blockIdx.z * kc;
    const int tx = threadIdx.x & 15;
    const int ty = threadIdx.x >> 4;
    float ar[4], wr[4];
#pragma unroll
    for (int r = 0; r < 4; ++r) {
        int idx = threadIdx.x + r * 256;
        int m = idx >> 4, kk = idx & 15;
        ar[r] = A[(size_t)(bm + m) * K + kz + kk];
        int n = idx & 63, kw = idx >> 6;
        wr[r] = W[(size_t)(kz + kw) * N + bn + n];
    }
    float acc[4][4] = {};
    for (int k0 = kz; k0 < kz + kc; k0 += 16) {
#pragma unroll
        for (int r = 0; r < 4; ++r) {
            int idx = threadIdx.x + r * 256;
            int m = idx >> 4, kk = idx & 15;
            As[kk][m] = ar[r];
            int n = idx & 63, kw = idx >> 6;
            Ws[kw][n] = wr[r];
        }
        __syncthreads();
        if (k0 + 16 < kz + kc) {   // prefetch next chunk into registers
#pragma unroll
            for (int r = 0; r < 4; ++r) {
                int idx = threadIdx.x + r * 256;
                int m = idx >> 4, kk = idx & 15;
                ar[r] = A[(size_t)(bm + m) * K + k0 + 16 + kk];
                int n = idx & 63, kw = idx >> 6;
                wr[r] = W[(size_t)(k0 + 16 + kw) * N + bn + n];
            }
        }
#pragma unroll
        for (int kk = 0; kk < 16; ++kk) {
            float4 av = *(const float4*)&As[kk][ty * 4];
            float4 bv = *(const float4*)&Ws[kk][tx * 4];
            float a[4] = {av.x, av.y, av.z, av.w};
            float b[4] = {bv.x, bv.y, bv.z, bv.w};
#pragma unroll
            for (int i = 0; i < 4; ++i)
#pragma unroll
                for (int j = 0; j < 4; ++j)
                    acc[i][j] = fmaf(a[i], b[j], acc[i][j]);
        }
        __syncthreads();
    }
    float* cp = Cp + (size_t)blockIdx.z * (size_t)(gridDim.y * 64) * N;
#pragma unroll
    for (int i = 0; i < 4; ++i) {
        int m = bm + ty * 4 + i;
#pragma unroll
        for (int j = 0; j < 4; ++j)
            cp[(size_t)m * N + bn + tx * 4 + j] = acc[i][j];
    }
}

// ---------------- gate+up combined split-K partial: 4 slices + prefetch --------
__global__ __launch_bounds__(256) void k_gu_part(const float* __restrict__ A,
                                                 const float* __restrict__ Wg,
                                                 const float* __restrict__ Wu,
                                                 float* __restrict__ GU) {
    __shared__ float As[16][68];
    __shared__ float Ws[16][68];
    const int bn = blockIdx.x * 64;
    const int bm = blockIdx.y * 64;
    const int z = blockIdx.z;
    const float* W = (z >> 1) ? Wu : Wg;
    const int kz = (z & 1) * 256;
    const int tx = threadIdx.x & 15;
    const int ty = threadIdx.x >> 4;
    float ar[4], wr[4];
#pragma unroll
    for (int r = 0; r < 4; ++r) {
        int idx = threadIdx.x + r * 256;
        int m = idx >> 4, kk = idx & 15;
        ar[r] = A[(size_t)(bm + m) * DMODEL + kz + kk];
        int n = idx & 63, kw = idx >> 6;
        wr[r] = W[(size_t)(kz + kw) * FF + bn + n];
    }
    float acc[4][4] = {};
    for (int k0 = kz; k0 < kz + 256; k0 += 16) {
#pragma unroll
        for (int r = 0; r < 4; ++r) {
            int idx = threadIdx.x + r * 256;
            int m = idx >> 4, kk = idx & 15;
            As[kk][m] = ar[r];
            int n = idx & 63, kw = idx >> 6;
            Ws[kw][n] = wr[r];
        }
        __syncthreads();
        if (k0 + 16 < kz + 256) {
#pragma unroll
            for (int r = 0; r < 4; ++r) {
                int idx = threadIdx.x + r * 256;
                int m = idx >> 4, kk = idx & 15;
                ar[r] = A[(size_t)(bm + m) * DMODEL + k0 + 16 + kk];
                int n = idx & 63, kw = idx >> 6;
                wr[r] = W[(size_t)(k0 + 16 + kw) * FF + bn + n];
            }
        }
#pragma unroll
        for (int kk = 0; kk < 16; ++kk) {
            float4 av = *(const float4*)&As[kk][ty * 4];
            float4 bv = *(const float4*)&Ws[kk][tx * 4];
            float a[4] = {av.x, av.y, av.z, av.w};
            float b[4] = {bv.x, bv.y, bv.z, bv.w};
#pragma unroll
            for (int i = 0; i < 4; ++i)
#pragma unroll
                for (int j = 0; j < 4; ++j)
                    acc[i][j] = fmaf(a[i], b[j], acc[i][j]);
        }
        __syncthreads();
    }
    float* cp = GU + (size_t)z * (NTOK * FF);
#pragma unroll
    for (int i = 0; i < 4; ++i) {
        int m = bm + ty * 4 + i;
#pragma unroll
        for (int j = 0; j < 4; ++j)
            cp[(size_t)m * FF + bn + tx * 4 + j] = acc[i][j];
    }
}

// ---------------- split-K elementwise reduce (+optional gelu) ----------------
__global__ void k_mm_finish(const float* __restrict__ Cp, const float* __restrict__ res,
                            float* __restrict__ C, int tot, int zstride, int nz, int act) {
    int i = blockIdx.x * 256 + threadIdx.x;
    if (i >= tot) return;
    float s = 0.f;
    for (int z = 0; z < nz; ++z) s += Cp[(size_t)z * zstride + i];
    if (res) s += res[i];
    if (act == 1) {  // gelu (tanh approx, jax default)
        float xg = s;
        float inner = 0.79788456080286536f * (xg + 0.044715f * xg * xg * xg);
        s = 0.5f * xg * (1.f + tanhf(inner));
    }
    C[i] = s;
}

// ---------------- reduce + silu(g)*u  (gate z=0..1, up z=2..3) ----------------
__global__ void k_finish_silumul(const float* __restrict__ GU, float* __restrict__ C) {
    int i = blockIdx.x * 256 + threadIdx.x;   // tot = 256*1536
    float g = GU[i] + GU[(size_t)(NTOK * FF) + i];
    float u = GU[(size_t)(2 * NTOK * FF) + i] + GU[(size_t)(3 * NTOK * FF) + i];
    float sig = 1.f / (1.f + expf(-g));
    C[i] = g * sig * u;
}

// ---------------- reduce + residual + dual write (raw, rmsnorm) ----------------
__global__ __launch_bounds__(256) void k_finish_norm(const float* __restrict__ Cp,
                                                     const float* __restrict__ res,
                                                     const float* __restrict__ normw,
                                                     float* __restrict__ out_raw,
                                                     float* __restrict__ out_norm,
                                                     int nz) {
    int row = blockIdx.x, t = threadIdx.x;
    int c0 = t, c1 = t + 256;
    size_t base = (size_t)row * DMODEL;
    float v0 = 0.f, v1 = 0.f;
    for (int z = 0; z < nz; ++z) {
        size_t zb = (size_t)z * (NTOK * DMODEL) + base;
        v0 += Cp[zb + c0];
        v1 += Cp[zb + c1];
    }
    v0 += res[base + c0];
    v1 += res[base + c1];
    float ss = v0 * v0 + v1 * v1;
    __shared__ float red[4];
    int lane = t & 63, wv = t >> 6;
    for (int o = 32; o > 0; o >>= 1) ss += __shfl_xor(ss, o);
    if (lane == 0) red[wv] = ss;
    __syncthreads();
    float tot = red[0] + red[1] + red[2] + red[3];
    float scale = rsqrtf(tot * (1.f / DMODEL) + EPSV);
    out_raw[base + c0] = v0;
    out_raw[base + c1] = v1;
    out_norm[base + c0] = v0 * scale * normw[c0];
    out_norm[base + c1] = v1 * scale * normw[c1];
}

// ---------------- qkv reduce + RoPE fused (z=4 slices, N=1536) ----------------
__global__ __launch_bounds__(256) void k_qkv_finish_rope(const float* __restrict__ Cp,
                                                         float* __restrict__ qkv) {
    int pos = blockIdx.x, t = threadIdx.x;
    int h = t >> 5, d = t & 31;
    size_t base = (size_t)pos * FF;
    auto S = [&](int col) {
        float s = 0.f;
#pragma unroll
        for (int z = 0; z < 4; ++z) s += Cp[(size_t)z * (NTOK * FF) + base + col];
        return s;
    };
    int cq0 = h * HD + d, cq1 = cq0 + HALF;
    int ck0 = DMODEL + cq0, ck1 = ck0 + HALF;
    int cv0 = 2 * DMODEL + t, cv1 = cv0 + 256;
    float q0 = S(cq0), q1 = S(cq1);
    float k0 = S(ck0), k1 = S(ck1);
    float v0 = S(cv0), v1 = S(cv1);
    float inv = powf(10000.f, -(float)d / 32.f);
    float ang = (float)pos * inv;
    float c = cosf(ang), s = sinf(ang);
    qkv[base + cq0] = q0 * c - q1 * s;
    qkv[base + cq1] = q0 * s + q1 * c;
    qkv[base + ck0] = k0 * c - k1 * s;
    qkv[base + ck1] = k0 * s + k1 * c;
    qkv[base + cv0] = v0;
    qkv[base + cv1] = v1;
}

// ---------------- attention: one block per (head, query) ----------------
__global__ __launch_bounds__(256) void k_attn(const float* __restrict__ qkv,
                                              float* __restrict__ out) {
    int h = blockIdx.x;
    int qi = blockIdx.y;
    int t = threadIdx.x;
    __shared__ float qs[HD];
    __shared__ float ps[NTOK];
    __shared__ float red[4];
    __shared__ float red2[4];
    __shared__ float os[4][HD];
    if (t < HD) qs[t] = qkv[(size_t)qi * FF + h * HD + t];
    __syncthreads();
    float sc = -1e30f;
    if (t <= qi) {
        const float* kr = qkv + (size_t)t * FF + DMODEL + h * HD;
        float s = 0.f;
        for (int d = 0; d < HD; ++d) s = fmaf(qs[d], kr[d], s);
        sc = s * 0.125f;
    }
    float m = sc;
    for (int o = 32; o > 0; o >>= 1) m = fmaxf(m, __shfl_xor(m, o));
    int lane = t & 63, wv = t >> 6;
    if (lane == 0) red[wv] = m;
    __syncthreads();
    m = fmaxf(fmaxf(red[0], red[1]), fmaxf(red[2], red[3]));
    float e = (t <= qi) ? expf(sc - m) : 0.f;
    ps[t] = e;
    float sum = e;
    for (int o = 32; o > 0; o >>= 1) sum += __shfl_xor(sum, o);
    if (lane == 0) red2[wv] = sum;
    __syncthreads();
    sum = red2[0] + red2[1] + red2[2] + red2[3];
    float inv = 1.f / sum;
    int d = t & 63, g = t >> 6;
    float acc = 0.f;
    for (int ki = g; ki <= qi; ki += 4)
        acc = fmaf(ps[ki], qkv[(size_t)ki * FF + 2 * DMODEL + h * HD + d], acc);
    os[g][d] = acc * inv;
    __syncthreads();
    if (t < HD)
        out[(size_t)qi * DMODEL + h * HD + t] = os[0][t] + os[1][t] + os[2][t] + os[3][t];
}

// ---------------- halt dots + ACT combine + A/B build, one block per token ----
__global__ __launch_bounds__(256) void k_haltactab(const float* __restrict__ H,
                                                   const float* __restrict__ wh,
                                                   const float* __restrict__ bptr,
                                                   float* __restrict__ ponder_out,
                                                   float* __restrict__ w_out,
                                                   __hip_bfloat16* __restrict__ A,
                                                   __hip_bfloat16* __restrict__ Bm) {
    int i = blockIdx.x, t = threadIdx.x;
    int lane = t & 63, wv = t >> 6;
    __shared__ float red[4];
    __shared__ float hvals[3];
    __shared__ float hw[4];
    for (int s = 1; s <= 3; ++s) {
        const float* hr = H + ((size_t)s * NTOK + i) * DMODEL;
        float a = hr[t] * wh[t] + hr[t + 256] * wh[t + 256];
        for (int o = 32; o > 0; o >>= 1) a += __shfl_xor(a, o);
        if (lane == 0) red[wv] = a;
        __syncthreads();
        if (t == 0)
            hvals[s - 1] = 1.f / (1.f + expf(-(red[0] + red[1] + red[2] + red[3] + bptr[0])));
        __syncthreads();
    }
    if (t == 0) {
        float p[4] = {0.f, hvals[0], hvals[1], hvals[2]};
        float cum = 0.f, rem = 0.f;
        int nrun = 0;
#pragma unroll
        for (int s = 0; s < 4; ++s) {
            float prev = cum;
            cum += p[s];
            bool running = prev < THR;
            bool use_rem = running && ((cum >= THR) || (s == 3));
            float v = 0.f;
            if (running) {
                v = use_rem ? (1.f - prev) : p[s];
                if (use_rem) rem += (1.f - prev);
                nrun++;
            }
            hw[s] = v;
            w_out[i * 4 + s] = v;
        }
        ponder_out[i] = (float)nrun + rem;
    }
    __syncthreads();
    float w0 = hw[0], w1 = hw[1], w2 = hw[2], w3 = hw[3];
    size_t base = (size_t)i * DMODEL;
#pragma unroll
    for (int r = 0; r < 2; ++r) {
        int d = t + r * 256;
        float h0 = H[base + d];
        float h1 = H[(size_t)(NTOK * DMODEL) + base + d];
        float h2 = H[(size_t)(2 * NTOK * DMODEL) + base + d];
        float h3 = H[(size_t)(3 * NTOK * DMODEL) + base + d];
        float h4 = H[(size_t)(4 * NTOK * DMODEL) + base + d];
        A[base + d]  = __float2bfloat16(w0 * h0 + w1 * h1 + w2 * h2 + w3 * h3);
        Bm[base + d] = __float2bfloat16(w0 * h1 + w1 * h2 + w2 * h3 + w3 * h4);
    }
}

// ---------------- final logits via 32x32x16 MFMA: out = A @ Wy + B @ Wd -------
// 8 waves = 4 row-groups (64 rows) x 2 col-tiles (32 cols); per wave-iter:
// 12 ds_read_b128, 0 scalar LDS reads, 8 MFMAs (was 16 b128 + 16 u16 + 16 MFMA
// with 16x16x32). Weight tiles transposed [col][40] (16B-aligned b128 frags,
// 4-way read / 2-way write banks); acts [256][40] (4-way reads, free writes).
// C/D layout (verified m74/m101): col=lane&31, row=(reg&3)+8*(reg>>2)+4*(lane>>5).
__global__ __launch_bounds__(512) void k_logits_mfma(const __hip_bfloat16* __restrict__ Abf,
                                                     const __hip_bfloat16* __restrict__ Bbf,
                                                     const float* __restrict__ Wy,
                                                     const float* __restrict__ Wd,
                                                     float* __restrict__ out) {
    __shared__ short Alds[256 * 40];   // 20 KB  [row][k] pad 40
    __shared__ short Blds[256 * 40];   // 20 KB
    __shared__ short Wys[64 * 40];     // 5 KB   [col][k] pad 40
    __shared__ short Wds[64 * 40];
    const int tid  = threadIdx.x;
    const int wave = tid >> 6;
    const int lane = tid & 63;
    const int l31  = lane & 31;
    const int hi8  = (lane >> 5) * 8;
    const int wv_row = (wave & 3) * 64;       // 64-row group
    const int wv_col = (wave >> 2) * 32;      // 32-col tile

    // act staging coords (rows 0..127 at i=0; +128 at i=1)
    const int sr0 = tid >> 2;
    const int skp = (tid & 3) * 8;
    // weight staging coords: thread covers col (tid&63), 4 k rows (tid>>6)*4
    const int wc  = tid & 63;
    const int wk4 = (tid >> 6) * 4;

    f32x16 acc0 = {};
    f32x16 acc1 = {};

    const size_t woff = (size_t)wk4 * VOCAB + blockIdx.x * 64 + wc;
    const float* gy = Wy + woff;
    const float* gd = Wd + woff;

    float rys[4], rds[4];
#pragma unroll
    for (int j = 0; j < 4; ++j) {
        rys[j] = gy[(size_t)j * VOCAB];
        rds[j] = gd[(size_t)j * VOCAB];
    }
    bf16x8 ra0 = *(const bf16x8*)(Abf + (size_t)sr0 * DMODEL + skp);
    bf16x8 ra1 = *(const bf16x8*)(Abf + (size_t)(sr0 + 128) * DMODEL + skp);
    bf16x8 rb0 = *(const bf16x8*)(Bbf + (size_t)sr0 * DMODEL + skp);
    bf16x8 rb1 = *(const bf16x8*)(Bbf + (size_t)(sr0 + 128) * DMODEL + skp);

    for (int t = 0; t < 16; ++t) {
        __syncthreads();  // previous iteration's fragment reads complete
        {
            short4 sy, sd;
            sy.x = f2b(rys[0]); sy.y = f2b(rys[1]); sy.z = f2b(rys[2]); sy.w = f2b(rys[3]);
            sd.x = f2b(rds[0]); sd.y = f2b(rds[1]); sd.z = f2b(rds[2]); sd.w = f2b(rds[3]);
            *(short4*)&Wys[wc * 40 + wk4] = sy;
            *(short4*)&Wds[wc * 40 + wk4] = sd;
            *(bf16x8*)&Alds[sr0 * 40 + skp]         = ra0;
            *(bf16x8*)&Alds[(sr0 + 128) * 40 + skp] = ra1;
            *(bf16x8*)&Blds[sr0 * 40 + skp]         = rb0;
            *(bf16x8*)&Blds[(sr0 + 128) * 40 + skp] = rb1;
        }
        if (t < 15) {  // prefetch next 32-k tile
            const int kn = (t + 1) * 32;
            const float* gy2 = gy + (size_t)kn * VOCAB;
            const float* gd2 = gd + (size_t)kn * VOCAB;
#pragma unroll
            for (int j = 0; j < 4; ++j) {
                rys[j] = gy2[(size_t)j * VOCAB];
                rds[j] = gd2[(size_t)j * VOCAB];
            }
            ra0 = *(const bf16x8*)(Abf + (size_t)sr0 * DMODEL + kn + skp);
            ra1 = *(const bf16x8*)(Abf + (size_t)(sr0 + 128) * DMODEL + kn + skp);
            rb0 = *(const bf16x8*)(Bbf + (size_t)sr0 * DMODEL + kn + skp);
            rb1 = *(const bf16x8*)(Bbf + (size_t)(sr0 + 128) * DMODEL + kn + skp);
        }
        __syncthreads();  // LDS tile visible
#pragma unroll
        for (int h = 0; h < 2; ++h) {
            const int klo = h * 16 + hi8;
            const bf16x8 wyf = *(const bf16x8*)&Wys[(wv_col + l31) * 40 + klo];
            const bf16x8 wdf = *(const bf16x8*)&Wds[(wv_col + l31) * 40 + klo];
            const bf16x8 ay0 = *(const bf16x8*)&Alds[(wv_row + l31) * 40 + klo];
            const bf16x8 ay1 = *(const bf16x8*)&Alds[(wv_row + 32 + l31) * 40 + klo];
            const bf16x8 ad0 = *(const bf16x8*)&Blds[(wv_row + l31) * 40 + klo];
            const bf16x8 ad1 = *(const bf16x8*)&Blds[(wv_row + 32 + l31) * 40 + klo];
            acc0 = __builtin_amdgcn_mfma_f32_32x32x16_bf16(ay0, wyf, acc0, 0, 0, 0);
            acc0 = __builtin_amdgcn_mfma_f32_32x32x16_bf16(ad0, wdf, acc0, 0, 0, 0);
            acc1 = __builtin_amdgcn_mfma_f32_32x32x16_bf16(ay1, wyf, acc1, 0, 0, 0);
            acc1 = __builtin_amdgcn_mfma_f32_32x32x16_bf16(ad1, wdf, acc1, 0, 0, 0);
        }
    }
    // C/D layout: col = lane&31, row = (reg&3) + 8*(reg>>2) + 4*(lane>>5)
    const int col = blockIdx.x * 64 + wv_col + l31;
    const int rbase = (lane >> 5) * 4;
#pragma unroll
    for (int reg = 0; reg < 16; ++reg) {
        int rowin = (reg & 3) + 8 * (reg >> 2) + rbase;
        out[(size_t)(wv_row + rowin) * VOCAB + col] = acc0[reg];
        out[(size_t)(wv_row + 32 + rowin) * VOCAB + col] = acc1[reg];
    }
}

extern "C" void kernel_launch(void* const* d_in, const int* in_sizes, int n_in,
                              void* d_out, int out_size, void* d_ws, size_t ws_size,
                              hipStream_t stream) {
    const int*   ids          = (const int*)d_in[0];
    const float* emb          = (const float*)d_in[1];
    const float* attn_norm_w  = (const float*)d_in[2];
    const float* mlp_norm_w   = (const float*)d_in[3];
    const float* wqkv         = (const float*)d_in[4];
    const float* wo           = (const float*)d_in[5];
    const float* w_gate       = (const float*)d_in[6];
    const float* w_up         = (const float*)d_in[7];
    const float* w_down       = (const float*)d_in[8];
    const float* final_norm_w = (const float*)d_in[9];
    const float* rc_norm_w    = (const float*)d_in[10];
    const float* rc_w1        = (const float*)d_in[11];
    const float* rc_w2        = (const float*)d_in[12];
    const float* w_y          = (const float*)d_in[13];
    const float* w_delta      = (const float*)d_in[14];
    const float* w_halt       = (const float*)d_in[15];
    const float* b_halt       = (const float*)d_in[16];
    float* out = (float*)d_out;

    float* ws = (float*)d_ws;
    // Live-range map (floats) — identical to round 10/12 (proven):
    //   x 0.. | xn 131072.. | qkv 262144.. | attnout 655360.. | g 786432..
    //   t1 1179648.. | states 1703936.. | states2 1835008.. | H 1966080..
    //   Abf 2623488.. | Bbf 2754560.. | Cp 2885632.. | GU 1179648.. (backbone only)
    float* x       = ws + 0;
    float* xn      = ws + 131072;
    float* qkv     = ws + 262144;
    float* attnout = ws + 655360;
    float* g       = ws + 786432;
    float* t1      = ws + 1179648;
    float* states  = ws + 1703936;
    float* states2 = ws + 1835008;
    float* H       = ws + 1966080;
    __hip_bfloat16* Abf = (__hip_bfloat16*)(ws + 2623488);
    __hip_bfloat16* Bbf = (__hip_bfloat16*)(ws + 2754560);
    float* Cp      = ws + 2885632;
    float* GU      = ws + 1179648;

    // ---------- backbone ----------
    k_embed_norm<<<NTOK, 256, 0, stream>>>(ids, emb, attn_norm_w, x, xn);
    for (int l = 0; l < NLAYER; ++l) {
        // qkv: K=512 N=1536, split 4 -> Cp; finish fused with RoPE
        k_mm_part<<<dim3(FF / 64, 4, 4), 256, 0, stream>>>(
            xn, wqkv + (size_t)l * DMODEL * FF, Cp, DMODEL, FF, 128);
        k_qkv_finish_rope<<<NTOK, 256, 0, stream>>>(Cp, qkv);
        k_attn<<<dim3(NHEAD, NTOK), 256, 0, stream>>>(qkv, attnout);
        // wo: K=512 N=512, split 8 -> Cp; finish fused with rmsnorm(mlp_norm)
        k_mm_part<<<dim3(DMODEL / 64, 4, 8), 256, 0, stream>>>(
            attnout, wo + (size_t)l * DMODEL * DMODEL, Cp, DMODEL, DMODEL, 64);
        k_finish_norm<<<NTOK, 256, 0, stream>>>(Cp, x, mlp_norm_w + l * DMODEL, x, xn, 8);
        // gate+up: one launch, 4 slices -> GU; reduce+silu*u -> g
        k_gu_part<<<dim3(FF / 64, 4, 4), 256, 0, stream>>>(
            xn, w_gate + (size_t)l * DMODEL * FF, w_up + (size_t)l * DMODEL * FF, GU);
        k_finish_silumul<<<NTOK * FF / 256, 256, 0, stream>>>(GU, g);
        // down: K=1536 N=512, split 12 -> Cp; finish fused with next norm
        k_mm_part<<<dim3(DMODEL / 64, 4, 12), 256, 0, stream>>>(
            g, w_down + (size_t)l * FF * DMODEL, Cp, FF, DMODEL, 128);
        const float* nw = (l == 0) ? (attn_norm_w + DMODEL) : final_norm_w;
        float* nout = (l == 0) ? xn : states;
        k_finish_norm<<<NTOK, 256, 0, stream>>>(Cp, x, nw, x, nout, 12);
    }

    // ---------- refinement steps (halt path stays f32) ----------
    k_rmsnorm<<<NTOK, 256, 0, stream>>>(states, rc_norm_w, H);
    float* scur = states;
    float* snxt = states2;
    for (int s = 0; s < NSTEPS; ++s) {
        // w1: K=512 N=2048, split 4 -> Cp; gelu in elementwise finish -> t1
        k_mm_part<<<dim3(RCFF / 64, 4, 4), 256, 0, stream>>>(
            H + (size_t)s * NTOK * DMODEL, rc_w1, Cp, DMODEL, RCFF, 128);
        k_mm_finish<<<NTOK * RCFF / 256, 256, 0, stream>>>(
            Cp, nullptr, t1, NTOK * RCFF, NTOK * RCFF, 4, 1);
        // w2: K=2048 N=512, split 16 -> Cp; finish fused residual+rmsnorm -> H_{s+1}
        k_mm_part<<<dim3(DMODEL / 64, 4, 16), 256, 0, stream>>>(
            t1, rc_w2, Cp, RCFF, DMODEL, 128);
        k_finish_norm<<<NTOK, 256, 0, stream>>>(
            Cp, scur, rc_norm_w, snxt, H + (size_t)(s + 1) * NTOK * DMODEL, 16);
        float* tmp = scur; scur = snxt; snxt = tmp;
    }

    // ---------- halt + ACT + A/B in one kernel ----------
    k_haltactab<<<NTOK, 256, 0, stream>>>(H, w_halt, b_halt,
                                          out + (size_t)NTOK * VOCAB,
                                          out + (size_t)NTOK * VOCAB + NTOK,
                                          Abf, Bbf);

    // ---------- final logits (MFMA 32x32x16 bf16, LDS-staged) ----------
    k_logits_mfma<<<VOCAB / 64, 512, 0, stream>>>(Abf, Bbf, w_y, w_delta, out);
}